// Round 6
// baseline (936.851 us; speedup 1.0000x reference)
//
#include <hip/hip_runtime.h>
#include <hip/hip_bf16.h>

// Shapes (fixed by the reference)
#define BB 2
#define HH 256
#define WWID 256
#define CC 96
#define NHEADS 6
#define WSZ 8
#define SHIFTV 4
#define HDIM 16
#define NTOK 64
#define HID 192
#define LL 65536   // H*W

using bf16 = __hip_bfloat16;
typedef short short8v __attribute__((ext_vector_type(8)));
typedef float float4v __attribute__((ext_vector_type(4)));

__device__ __forceinline__ float b2f(bf16 v){ return __bfloat162float(v); }
__device__ __forceinline__ bf16  f2b(float f){ return __float2bfloat16(f); }
__device__ __forceinline__ float blo(unsigned u){ union {unsigned x; float f;} c; c.x = u << 16; return c.f; }
__device__ __forceinline__ float bhi(unsigned u){ union {unsigned x; float f;} c; c.x = u & 0xffff0000u; return c.f; }

__device__ __forceinline__ float dot8(uint4 a, uint4 b, float acc){
  acc += blo(a.x)*blo(b.x); acc += bhi(a.x)*bhi(b.x);
  acc += blo(a.y)*blo(b.y); acc += bhi(a.y)*bhi(b.y);
  acc += blo(a.z)*blo(b.z); acc += bhi(a.z)*bhi(b.z);
  acc += blo(a.w)*blo(b.w); acc += bhi(a.w)*bhi(b.w);
  return acc;
}

// async 16B global->LDS DMA (dest = wave-uniform base + lane*16)
__device__ __forceinline__ void gload16(const void* g, void* l){
  __builtin_amdgcn_global_load_lds(
      (const __attribute__((address_space(1))) unsigned int*)g,
      (__attribute__((address_space(3))) unsigned int*)l, 16, 0, 0);
}

// LDS granule swizzle (pitch 12 granules of 16B).
__device__ __forceinline__ int swz(int c8, int r){
  return (c8 < 8) ? (c8 ^ (r & 7)) : (8 + ((c8 & 3) ^ ((r >> 1) & 3)));
}

// ---------------- input dtype detection -------------------------------------
__global__ void detect_kernel(const unsigned* __restrict__ x, int* __restrict__ flag){
  __shared__ int s[256];
  int t = threadIdx.x;
  int cnt = 0;
  #pragma unroll
  for (int i = 0; i < 4; ++i){
    unsigned u = x[t*4 + i];
    unsigned e = (u >> 7) & 0xFFu;
    cnt += (e >= 118u && e <= 130u) ? 1 : 0;
  }
  s[t] = cnt; __syncthreads();
  for (int m = 128; m > 0; m >>= 1){ if (t < m) s[t] += s[t+m]; __syncthreads(); }
  if (t == 0) *flag = (s[0] < 512) ? 1 : 0;
}

// ---------------- convert all inputs into one packed bf16 block -------------
struct CvtArgs { const void* src[21]; long cum[22]; long cumP[22]; };

__global__ void cvt_kernel(CvtArgs a, const int* __restrict__ flag,
                           bf16* __restrict__ dst, long totalP){
  long k0 = ((long)blockIdx.x * 256 + threadIdx.x) * 8;
  if (k0 >= totalP) return;
  int lo = 0;
  #pragma unroll
  for (int i = 0; i < 21; ++i) if (k0 >= a.cumP[i+1]) lo = i+1;
  long e = k0 - a.cumP[lo];
  long n = a.cum[lo+1] - a.cum[lo];
  int f = *flag;
  __align__(16) bf16 ob[8];
  if (e + 8 <= n){
    if (f){
      const float* s = (const float*)a.src[lo] + e;
      float4 v0 = *(const float4*)s;
      float4 v1 = *(const float4*)(s + 4);
      ob[0]=f2b(v0.x); ob[1]=f2b(v0.y); ob[2]=f2b(v0.z); ob[3]=f2b(v0.w);
      ob[4]=f2b(v1.x); ob[5]=f2b(v1.y); ob[6]=f2b(v1.z); ob[7]=f2b(v1.w);
    } else {
      *(uint4*)ob = *(const uint4*)((const bf16*)a.src[lo] + e);
    }
  } else {
    #pragma unroll
    for (int j = 0; j < 8; ++j){
      long ee = e + j;
      ob[j] = (ee < n) ? (f ? f2b(((const float*)a.src[lo])[ee])
                            : ((const bf16*)a.src[lo])[ee])
                       : f2b(0.f);
    }
  }
  *(uint4*)&dst[k0] = *(uint4*)ob;
}

// ---------------- weight prepack: w[tap][cin][cout] -> swizzled LDS image ---
__global__ void wprep_kernel(const bf16* __restrict__ w, bf16* __restrict__ out,
                             int CINr, int COUTr, long total){
  long k = (long)blockIdx.x * 256 + threadIdx.x;
  if (k >= total) return;
  int NHr = COUTr / 96, CHr = CINr / 96;
  int region = (int)(k / 10240); int rem = (int)(k - (long)region*10240);
  int gg = rem >> 3, e = rem & 7;
  if (gg >= 1152){ out[k] = f2b(0.f); return; }
  int r = gg / 12, pos = gg - r*12;
  int ch = region % CHr; int t2 = region / CHr;
  int nhh = t2 % NHr; int tap = t2 / NHr;
  int c8 = (pos < 8) ? (pos ^ (r & 7)) : (8 + ((pos & 3) ^ ((r >> 1) & 3)));
  int cin = ch*96 + c8*8 + e;
  int cout = nhh*96 + r;
  out[k] = w[((long)tap*CINr + cin)*COUTr + cout];
}

// ---------------- LayerNorm1 on x and ref (bf16 in -> bf16 out) -------------
__global__ __launch_bounds__(256) void ln1_kernel(const bf16* __restrict__ x, const bf16* __restrict__ ref,
                                                  const bf16* __restrict__ g, const bf16* __restrict__ bt,
                                                  bf16* __restrict__ xn, bf16* __restrict__ rn)
{
  int wave = threadIdx.x >> 6, lane = threadIdx.x & 63;
  long row = (long)blockIdx.x * 4 + wave;         // 0 .. 2*BB*LL-1
  const bf16* src; bf16* dst; long r;
  if (row < (long)BB*LL){ src = x; dst = xn; r = row; }
  else                  { src = ref; dst = rn; r = row - (long)BB*LL; }
  const bf16* p = src + r*CC;
  float v0 = b2f(p[lane]);
  float v1 = (lane < 32) ? b2f(p[64+lane]) : 0.f;
  float s = v0 + v1;
  #pragma unroll
  for (int m = 32; m >= 1; m >>= 1) s += __shfl_xor(s, m, 64);
  float mu = s * (1.f/CC);
  float d0 = v0 - mu, d1 = v1 - mu;
  float ss = d0*d0 + ((lane < 32) ? d1*d1 : 0.f);
  #pragma unroll
  for (int m = 32; m >= 1; m >>= 1) ss += __shfl_xor(ss, m, 64);
  float rstd = rsqrtf(ss * (1.f/CC) + 1e-5f);
  bf16* q = dst + r*CC;
  q[lane] = f2b(d0 * rstd * b2f(g[lane]) + b2f(bt[lane]));
  if (lane < 32) q[64+lane] = f2b(d1 * rstd * b2f(g[64+lane]) + b2f(bt[64+lane]));
}

// ---------------- LayerNorm2 (bf16 in -> bf16 out) --------------------------
__global__ __launch_bounds__(256) void ln2_kernel(const bf16* __restrict__ xin,
                                                  const bf16* __restrict__ g, const bf16* __restrict__ bt,
                                                  bf16* __restrict__ out)
{
  int wave = threadIdx.x >> 6, lane = threadIdx.x & 63;
  long r = (long)blockIdx.x * 4 + wave;           // 0 .. BB*LL-1
  const bf16* p = xin + r*CC;
  float v0 = b2f(p[lane]);
  float v1 = (lane < 32) ? b2f(p[64+lane]) : 0.f;
  float s = v0 + v1;
  #pragma unroll
  for (int m = 32; m >= 1; m >>= 1) s += __shfl_xor(s, m, 64);
  float mu = s * (1.f/CC);
  float d0 = v0 - mu, d1 = v1 - mu;
  float ss = d0*d0 + ((lane < 32) ? d1*d1 : 0.f);
  #pragma unroll
  for (int m = 32; m >= 1; m >>= 1) ss += __shfl_xor(ss, m, 64);
  float rstd = rsqrtf(ss * (1.f/CC) + 1e-5f);
  bf16* q = out + r*CC;
  q[lane] = f2b(d0 * rstd * b2f(g[lane]) + b2f(bt[lane]));
  if (lane < 32) q[64+lane] = f2b(d1 * rstd * b2f(g[64+lane]) + b2f(bt[64+lane]));
}

// ---------------- Fused window attention, MFMA everywhere -------------------
// v2: swapped QK^T (lane holds a full q-row of S) -> softmax = local max +
//     2 shuffles; P written as packed b64. l2-norm fused in-register into the
//     QKV epilogue. wb/ps share one LDS region (phases barrier-separated).
//     LDS 54,152 B -> 3 blocks/CU.
__global__ __launch_bounds__(256) void attn_kernel(const bf16* __restrict__ xn, const bf16* __restrict__ rn,
                                                   const bf16* __restrict__ qkv_w, const bf16* __restrict__ qkv_b,
                                                   const bf16* __restrict__ lsc, const bf16* __restrict__ gat,
                                                   const bf16* __restrict__ rpbt, bf16* __restrict__ img)
{
  __shared__ __align__(16) bf16 sx[NTOK][104];    // 13312 B
  __shared__ __align__(16) bf16 sr[NTOK][104];    // 13312 B
  __shared__ __align__(16) bf16 wps[48*104];      //  9984 B  union: wb[48][104] / ps[64][72]
  __shared__ float sbias[48];                     //   192 B
  __shared__ __align__(16) bf16 qs[NTOK][32];     //  4096 B  qn (d 16..31 zero)
  __shared__ __align__(16) bf16 ks[NTOK][32];     //  4096 B  kn
  __shared__ __align__(16) bf16 krs[NTOK][32];    //  4096 B  kn_ref
  __shared__ __align__(16) bf16 vt[16][72];       //  2304 B  V^T [d][tok]
  __shared__ __align__(16) bf16 vrt[16][72];      //  2304 B  Vr^T
  __shared__ __align__(16) bf16 rpbs[228];        //   456 B  rpb head slice (bf16)

  bf16 (*wb)[104] = (bf16(*)[104])&wps[0];
  bf16 (*ps)[72]  = (bf16(*)[72])&wps[0];

  int widx = blockIdx.x;
  int b = widx >> 10, wib = widx & 1023;
  int wh = wib >> 5, ww = wib & 31;
  int tid = threadIdx.x;
  int wv = tid >> 6, lane = tid & 63;
  int ml = lane & 15, quad = lane >> 4;

  for (int idx = tid; idx < NTOK*12; idx += 256){
    int n = idx / 12, c8 = idx - n*12;
    int i = n >> 3, j = n & 7;
    int h0 = (wh*8 + i + SHIFTV) & 255;
    int w0 = (ww*8 + j + SHIFTV) & 255;
    long base = (((long)b*HH + h0)*WWID + w0)*CC + c8*8;
    *(uint4*)&sx[n][c8*8] = *(const uint4*)&xn[base];
    *(uint4*)&sr[n][c8*8] = *(const uint4*)&rn[base];
  }
  for (int idx = tid; idx < 384; idx += 256){
    int arr = idx >> 7, rem = idx & 127;
    int row = rem >> 1, half = rem & 1;
    bf16* bp = (arr == 0) ? &qs[0][0] : (arr == 1) ? &ks[0][0] : &krs[0][0];
    *(uint4*)&bp[row*32 + 16 + half*8] = make_uint4(0,0,0,0);
  }

  for (int h = 0; h < NHEADS; ++h){
    __syncthreads();  // prev head's ps/qs/vt reads done before restage
    for (int idx = tid; idx < 48*12; idx += 256){
      int rr = idx / 12, c8 = idx - rr*12;
      int o = (rr >> 4)*CC + h*HDIM + (rr & 15);
      *(uint4*)&wb[rr][c8*8] = *(const uint4*)&qkv_w[(long)o*CC + c8*8];
    }
    if (tid < 48){
      int o = (tid >> 4)*CC + h*HDIM + (tid & 15);
      sbias[tid] = b2f(qkv_b[o]);
    }
    if (tid < 225) rpbs[tid] = rpbt[tid*NHEADS + h];
    __syncthreads();

    // ---- QKV via MFMA: wave wv owns token rows wv*16..+15 ----
    float4v aq0 = {0,0,0,0}, aq1 = {0,0,0,0}, aq2 = {0,0,0,0};
    float4v ar0 = {0,0,0,0}, ar1 = {0,0,0,0};
    {
      int arow = wv*16 + ml;
      #pragma unroll
      for (int kt = 0; kt < 3; ++kt){
        int ko = kt*32 + quad*8;
        short8v ax = *(const short8v*)&sx[arow][ko];
        short8v av = *(const short8v*)&sr[arow][ko];
        short8v b0 = *(const short8v*)&wb[ml][ko];
        short8v b1 = *(const short8v*)&wb[16+ml][ko];
        short8v b2 = *(const short8v*)&wb[32+ml][ko];
        aq0 = __builtin_amdgcn_mfma_f32_16x16x32_bf16(ax, b0, aq0, 0,0,0);
        aq1 = __builtin_amdgcn_mfma_f32_16x16x32_bf16(ax, b1, aq1, 0,0,0);
        aq2 = __builtin_amdgcn_mfma_f32_16x16x32_bf16(ax, b2, aq2, 0,0,0);
        ar0 = __builtin_amdgcn_mfma_f32_16x16x32_bf16(av, b1, ar0, 0,0,0);
        ar1 = __builtin_amdgcn_mfma_f32_16x16x32_bf16(av, b2, ar1, 0,0,0);
      }
    }
    // ---- epilogue: bias + in-register l2 norm (reduce over ml lanes) ----
    {
      float bq = sbias[ml], bk = sbias[16+ml], bv = sbias[32+ml];
      #pragma unroll
      for (int r = 0; r < 4; ++r){
        float qv  = aq0[r] + bq;
        float kv  = aq1[r] + bk;
        float krv = ar0[r] + bk;
        float sq = qv*qv, sk = kv*kv, skr = krv*krv;
        #pragma unroll
        for (int m = 1; m < 16; m <<= 1){
          sq  += __shfl_xor(sq,  m, 64);
          sk  += __shfl_xor(sk,  m, 64);
          skr += __shfl_xor(skr, m, 64);
        }
        float iq  = 1.f / fmaxf(sqrtf(sq),  1e-12f);
        float ik  = 1.f / fmaxf(sqrtf(sk),  1e-12f);
        float ikr = 1.f / fmaxf(sqrtf(skr), 1e-12f);
        int tok = wv*16 + quad*4 + r;
        qs[tok][ml]  = f2b(qv*iq);
        ks[tok][ml]  = f2b(kv*ik);
        krs[tok][ml] = f2b(krv*ikr);
        vt[ml][tok]  = f2b(aq2[r] + bv);
        vrt[ml][tok] = f2b(ar1[r] + bv);
      }
    }
    __syncthreads();

    float ls = expf(fminf(b2f(lsc[h]), 4.605170185988091f));
    float gv = b2f(gat[h]);
    float g = 1.f / (1.f + expf(-gv));

    // ---- S^T via swapped MFMA: s1[nt][r] = S[wv*16+ml][nt*16+quad*4+r] ----
    float4v s1[4], s2[4];
    {
      short8v qf = *(const short8v*)&qs[wv*16 + ml][quad*8];
      #pragma unroll
      for (int nt = 0; nt < 4; ++nt){
        short8v kf  = *(const short8v*)&ks[nt*16 + ml][quad*8];
        short8v krf = *(const short8v*)&krs[nt*16 + ml][quad*8];
        float4v z = {0,0,0,0};
        s1[nt] = __builtin_amdgcn_mfma_f32_16x16x32_bf16(kf,  qf, z, 0,0,0);
        s2[nt] = __builtin_amdgcn_mfma_f32_16x16x32_bf16(krf, qf, z, 0,0,0);
      }
    }
    // ---- scale, rpb, mask; one q-row per lane ----
    int ti = wv*16 + ml;
    int iy = ti >> 3, ix = ti & 7;
    int regi = ((wh < 31) ? 0 : (iy < 4 ? 1 : 2))*3 + ((ww < 31) ? 0 : (ix < 4 ? 1 : 2));
    float sv1[4][4], sv2[4][4];
    #pragma unroll
    for (int nt = 0; nt < 4; ++nt){
      #pragma unroll
      for (int r = 0; r < 4; ++r){
        int tj = nt*16 + quad*4 + r;
        int jy = tj >> 3, jx = tj & 7;
        int regj = ((wh < 31) ? 0 : (jy < 4 ? 1 : 2))*3 + ((ww < 31) ? 0 : (jx < 4 ? 1 : 2));
        float rp = b2f(rpbs[(iy - jy + 7)*15 + (ix - jx + 7)]);
        float msk = (regi != regj) ? -100.f : 0.f;
        sv1[nt][r] = s1[nt][r]*ls + rp + msk;
        sv2[nt][r] = s2[nt][r]*ls + rp + msk;
      }
    }
    // ---- softmax: local 16-max + 2 cross-quad shuffles ----
    float mx1 = -1e30f, mx2 = -1e30f;
    #pragma unroll
    for (int nt = 0; nt < 4; ++nt)
      #pragma unroll
      for (int r = 0; r < 4; ++r){ mx1 = fmaxf(mx1, sv1[nt][r]); mx2 = fmaxf(mx2, sv2[nt][r]); }
    mx1 = fmaxf(mx1, __shfl_xor(mx1, 16, 64)); mx1 = fmaxf(mx1, __shfl_xor(mx1, 32, 64));
    mx2 = fmaxf(mx2, __shfl_xor(mx2, 16, 64)); mx2 = fmaxf(mx2, __shfl_xor(mx2, 32, 64));
    float sm1 = 0.f, sm2 = 0.f;
    #pragma unroll
    for (int nt = 0; nt < 4; ++nt)
      #pragma unroll
      for (int r = 0; r < 4; ++r){
        sv1[nt][r] = expf(sv1[nt][r] - mx1); sm1 += sv1[nt][r];
        sv2[nt][r] = expf(sv2[nt][r] - mx2); sm2 += sv2[nt][r];
      }
    sm1 += __shfl_xor(sm1, 16, 64); sm1 += __shfl_xor(sm1, 32, 64);
    sm2 += __shfl_xor(sm2, 16, 64); sm2 += __shfl_xor(sm2, 32, 64);
    float f1 = (1.f - g) / sm1;
    float f2 = g / sm2;

    // ---- PV path 1: packed b64 P writes (wave-private rows) ----
    #pragma unroll
    for (int nt = 0; nt < 4; ++nt){
      __align__(8) bf16 pk[4];
      #pragma unroll
      for (int r = 0; r < 4; ++r) pk[r] = f2b(sv1[nt][r] * f1);
      *(short4*)&ps[ti][nt*16 + quad*4] = *(short4*)pk;
    }
    float4v po = {0,0,0,0};
    #pragma unroll
    for (int kt = 0; kt < 2; ++kt){
      short8v pa = *(const short8v*)&ps[wv*16 + ml][kt*32 + quad*8];
      short8v vb = *(const short8v*)&vt[ml][kt*32 + quad*8];
      po = __builtin_amdgcn_mfma_f32_16x16x32_bf16(pa, vb, po, 0,0,0);
    }
    // ---- PV path 2 (reuse ps) ----
    #pragma unroll
    for (int nt = 0; nt < 4; ++nt){
      __align__(8) bf16 pk[4];
      #pragma unroll
      for (int r = 0; r < 4; ++r) pk[r] = f2b(sv2[nt][r] * f2);
      *(short4*)&ps[ti][nt*16 + quad*4] = *(short4*)pk;
    }
    #pragma unroll
    for (int kt = 0; kt < 2; ++kt){
      short8v pa = *(const short8v*)&ps[wv*16 + ml][kt*32 + quad*8];
      short8v vb = *(const short8v*)&vrt[ml][kt*32 + quad*8];
      po = __builtin_amdgcn_mfma_f32_16x16x32_bf16(pa, vb, po, 0,0,0);
    }
    // ---- write out (shifted coords); po[r] = O[wv*16+quad*4+r][ml] ----
    #pragma unroll
    for (int r = 0; r < 4; ++r){
      int tok = wv*16 + quad*4 + r;
      int hs = wh*8 + (tok >> 3), wsp = ww*8 + (tok & 7);
      img[(((long)b*HH + hs)*WWID + wsp)*CC + h*HDIM + ml] = f2b(po[r]);
    }
  }
}

// ---------------- MFMA implicit-GEMM 3x3 conv (NHWC, pad 1) -----------------
template<int CIN, int COUT, int MODE>
__global__ __launch_bounds__(256) void convmfma_kernel(const bf16* __restrict__ src,
                                                       const bf16* __restrict__ wtp,
                                                       const bf16* __restrict__ bias,
                                                       const bf16* __restrict__ base,
                                                       bf16* __restrict__ dst)
{
  constexpr int CH = CIN / 96;
  constexpr int NH = COUT / 96;
  constexpr int NS = CH * 9;
  __shared__ __align__(16) bf16 act[180*12*8];   // 34,560 B
  __shared__ __align__(16) bf16 wl[2][1280*8];   // 2 x 20,480 B

  int tid = threadIdx.x;
  int z = blockIdx.z;
  int bb = z / NH;
  int nh = z % NH;
  int tx0 = blockIdx.x * 16, ty0 = blockIdx.y * 8;
  int wv = tid >> 6, lane = tid & 63;

  auto stage_act = [&](int h){
    for (int idx = tid; idx < 180*12; idx += 256){
      int pp = idx / 12, c8 = idx - pp*12;
      int iy = pp / 18, ix = pp - iy*18;
      int gy = ty0 + iy - 1, gx = tx0 + ix - 1;
      uint4 v = make_uint4(0,0,0,0);
      if ((unsigned)gy < (unsigned)HH && (unsigned)gx < (unsigned)WWID)
        v = *(const uint4*)&src[(((long)bb*HH + gy)*WWID + gx)*CIN + h*96 + c8*8];
      *(uint4*)&act[(pp*12 + swz(c8, pp))*8] = v;
    }
  };
  auto gloadW = [&](int s, int buf){
    int hh = s / 9, tap = s - hh*9;
    int region = (tap*NH + nh)*CH + hh;
    const bf16* g = wtp + (long)region*10240 + (wv*320 + lane)*8;
    bf16* l = &wl[buf][(wv*320)*8];
    #pragma unroll
    for (int i = 0; i < 5; ++i)
      gload16(g + i*512, l + i*512);
  };

  int wm = wv >> 1, wn = wv & 1;
  int ml = lane & 15, quad = lane >> 4;

  float4v acc[4][3];
  #pragma unroll
  for (int nt = 0; nt < 3; ++nt){
    float bv = b2f(bias[nh*96 + wn*48 + nt*16 + ml]);
    #pragma unroll
    for (int mt = 0; mt < 4; ++mt)
      acc[mt][nt] = (float4v){bv, bv, bv, bv};
  }

  int apy = ml >> 3, apx = wm*8 + (ml & 7);

  stage_act(0);
  gloadW(0, 0);
  if (NS > 1) gloadW(1, 1);
  __syncthreads();

  for (int s = 0; s < NS; ++s){
    int h = s / 9, tap = s - h*9;
    int cur = s & 1;
    int dy = tap / 3, dx = tap - dy*3;
    #pragma unroll
    for (int kc = 0; kc < 3; ++kc){
      int posB = (kc < 2) ? ((kc*4 + quad) ^ (ml & 7)) : (8 + (quad ^ ((ml >> 1) & 3)));
      int brow = wn*48 + ml;
      short8v b0 = *(const short8v*)&wl[cur][((brow     )*12 + posB)*8];
      short8v b1 = *(const short8v*)&wl[cur][((brow + 16)*12 + posB)*8];
      short8v b2 = *(const short8v*)&wl[cur][((brow + 32)*12 + posB)*8];
      #pragma unroll
      for (int mt = 0; mt < 4; ++mt){
        int pp = (mt*2 + apy + dy)*18 + apx + dx;
        int posA = (kc < 2) ? ((kc*4 + quad) ^ (pp & 7)) : (8 + (quad ^ ((pp >> 1) & 3)));
        short8v a = *(const short8v*)&act[(pp*12 + posA)*8];
        acc[mt][0] = __builtin_amdgcn_mfma_f32_16x16x32_bf16(a, b0, acc[mt][0], 0, 0, 0);
        acc[mt][1] = __builtin_amdgcn_mfma_f32_16x16x32_bf16(a, b1, acc[mt][1], 0, 0, 0);
        acc[mt][2] = __builtin_amdgcn_mfma_f32_16x16x32_bf16(a, b2, acc[mt][2], 0, 0, 0);
      }
    }
    if (s + 1 == NS) break;
    __syncthreads();
    if (s + 2 < NS) gloadW(s + 2, cur);
    if (tap == 8){
      stage_act(h + 1);
      __syncthreads();
    }
  }

  #pragma unroll
  for (int mt = 0; mt < 4; ++mt){
    #pragma unroll
    for (int r = 0; r < 4; ++r){
      int mrow = quad*4 + r;
      int py = mt*2 + (mrow >> 3), px = wm*8 + (mrow & 7);
      long ob = (((long)bb*HH + ty0+py)*WWID + tx0+px)*COUT + nh*96 + wn*48 + ml;
      #pragma unroll
      for (int nt = 0; nt < 3; ++nt){
        float v = acc[mt][nt][r];
        long o = ob + nt*16;
        if (MODE == 0)      dst[o] = f2b(fmaxf(v, 0.f));
        else if (MODE == 1) dst[o] = f2b(b2f(base[o]) + v);
        else                dst[o] = f2b(0.5f * v * (1.f + erff(v * 0.7071067811865476f)));
      }
    }
  }
}

// ---------------- proj (96x96) + roll-back(+4,+4) + shortcut -> bf16 xmid ---
#define PPITCH (CC+8)
__global__ __launch_bounds__(256) void proj_kernel(const bf16* __restrict__ img, const bf16* __restrict__ pw,
                                                   const bf16* __restrict__ pb, const bf16* __restrict__ xorig,
                                                   bf16* __restrict__ xmid)
{
  __shared__ __align__(16) bf16 rows[64][PPITCH];
  __shared__ __align__(16) bf16 wsm[CC][PPITCH];
  long pix0 = (long)blockIdx.x * 64;
  int tid = threadIdx.x;
  for (int idx = tid; idx < 64*CC; idx += 256){
    int pp = idx / CC, c = idx - pp*CC;
    long pix = pix0 + pp;
    int b = (int)(pix >> 16); int hw = (int)(pix & 65535);
    int h = hw >> 8, wc = hw & 255;
    int sh = (h - SHIFTV) & 255, sw = (wc - SHIFTV) & 255;
    rows[pp][c] = img[(((long)b*HH + sh)*WWID + sw)*CC + c];
  }
  for (int idx = tid; idx < CC*CC; idx += 256){
    int rr = idx / CC, c = idx - rr*CC;
    wsm[rr][c] = pw[idx];
  }
  __syncthreads();
  int ty = tid >> 4, tx = tid & 15;
  int r0 = ty*4;
  float acc[4][6];
  #pragma unroll
  for (int j = 0; j < 6; ++j){
    float bv = b2f(pb[tx + 16*j]);
    #pragma unroll
    for (int i = 0; i < 4; ++i) acc[i][j] = bv;
  }
  for (int kk = 0; kk < 12; ++kk){
    uint4 a0 = ((const uint4*)rows[r0+0])[kk];
    uint4 a1 = ((const uint4*)rows[r0+1])[kk];
    uint4 a2 = ((const uint4*)rows[r0+2])[kk];
    uint4 a3 = ((const uint4*)rows[r0+3])[kk];
    #pragma unroll
    for (int j = 0; j < 6; ++j){
      uint4 wv = ((const uint4*)wsm[tx + 16*j])[kk];
      acc[0][j] = dot8(a0, wv, acc[0][j]);
      acc[1][j] = dot8(a1, wv, acc[1][j]);
      acc[2][j] = dot8(a2, wv, acc[2][j]);
      acc[3][j] = dot8(a3, wv, acc[3][j]);
    }
  }
  #pragma unroll
  for (int i = 0; i < 4; ++i){
    long pix = pix0 + r0 + i;
    #pragma unroll
    for (int j = 0; j < 6; ++j){
      long oi = pix*CC + tx + 16*j;
      xmid[oi] = f2b(b2f(xorig[oi]) + acc[i][j]);
    }
  }
}

// ---------------- fc1: 96->192 + exact GELU ---------------------------------
__global__ __launch_bounds__(256) void fc1_kernel(const bf16* __restrict__ src, const bf16* __restrict__ w,
                                                  const bf16* __restrict__ bias, bf16* __restrict__ dst)
{
  __shared__ __align__(16) bf16 rows[64][PPITCH];
  __shared__ __align__(16) bf16 wsm[HID][PPITCH];
  long pix0 = (long)blockIdx.x * 64;
  int tid = threadIdx.x;
  for (int idx = tid; idx < 64*CC; idx += 256){
    int pp = idx / CC, c = idx - pp*CC;
    rows[pp][c] = src[(pix0 + pp)*CC + c];
  }
  for (int idx = tid; idx < HID*CC; idx += 256){
    int rr = idx / CC, c = idx - rr*CC;
    wsm[rr][c] = w[idx];
  }
  __syncthreads();
  int ty = tid >> 4, tx = tid & 15;
  int r0 = ty*4;
  float acc[4][12];
  #pragma unroll
  for (int j = 0; j < 12; ++j){
    float bv = b2f(bias[tx + 16*j]);
    #pragma unroll
    for (int i = 0; i < 4; ++i) acc[i][j] = bv;
  }
  for (int kk = 0; kk < 12; ++kk){
    uint4 a0 = ((const uint4*)rows[r0+0])[kk];
    uint4 a1 = ((const uint4*)rows[r0+1])[kk];
    uint4 a2 = ((const uint4*)rows[r0+2])[kk];
    uint4 a3 = ((const uint4*)rows[r0+3])[kk];
    #pragma unroll
    for (int j = 0; j < 12; ++j){
      uint4 wv = ((const uint4*)wsm[tx + 16*j])[kk];
      acc[0][j] = dot8(a0, wv, acc[0][j]);
      acc[1][j] = dot8(a1, wv, acc[1][j]);
      acc[2][j] = dot8(a2, wv, acc[2][j]);
      acc[3][j] = dot8(a3, wv, acc[3][j]);
    }
  }
  #pragma unroll
  for (int i = 0; i < 4; ++i){
    long pix = pix0 + r0 + i;
    #pragma unroll
    for (int j = 0; j < 12; ++j){
      float v = acc[i][j];
      dst[pix*HID + tx + 16*j] = f2b(0.5f * v * (1.f + erff(v * 0.7071067811865476f)));
    }
  }
}

// ---------------- fc2: 192->96 + bf16 xmid residual -> out (flag dtype) -----
#define FPITCH (HID+8)
__global__ __launch_bounds__(256) void fc2_kernel(const bf16* __restrict__ src, const bf16* __restrict__ w,
                                                  const bf16* __restrict__ bias, const bf16* __restrict__ xmid,
                                                  void* __restrict__ outv, const int* __restrict__ flag)
{
  __shared__ __align__(16) bf16 rows[64][FPITCH];
  __shared__ __align__(16) bf16 wsm[CC][FPITCH];
  long pix0 = (long)blockIdx.x * 64;
  int tid = threadIdx.x;
  for (int idx = tid; idx < 64*HID; idx += 256){
    int pp = idx / HID, c = idx - pp*HID;
    rows[pp][c] = src[(pix0 + pp)*HID + c];
  }
  for (int idx = tid; idx < CC*HID; idx += 256){
    int rr = idx / HID, c = idx - rr*HID;
    wsm[rr][c] = w[idx];
  }
  __syncthreads();
  int ty = tid >> 4, tx = tid & 15;
  int r0 = ty*4;
  float acc[4][6];
  #pragma unroll
  for (int j = 0; j < 6; ++j){
    float bv = b2f(bias[tx + 16*j]);
    #pragma unroll
    for (int i = 0; i < 4; ++i) acc[i][j] = bv;
  }
  for (int kk = 0; kk < 24; ++kk){
    uint4 a0 = ((const uint4*)rows[r0+0])[kk];
    uint4 a1 = ((const uint4*)rows[r0+1])[kk];
    uint4 a2 = ((const uint4*)rows[r0+2])[kk];
    uint4 a3 = ((const uint4*)rows[r0+3])[kk];
    #pragma unroll
    for (int j = 0; j < 6; ++j){
      uint4 wv = ((const uint4*)wsm[tx + 16*j])[kk];
      acc[0][j] = dot8(a0, wv, acc[0][j]);
      acc[1][j] = dot8(a1, wv, acc[1][j]);
      acc[2][j] = dot8(a2, wv, acc[2][j]);
      acc[3][j] = dot8(a3, wv, acc[3][j]);
    }
  }
  int f = *flag;
  #pragma unroll
  for (int i = 0; i < 4; ++i){
    long pix = pix0 + r0 + i;
    #pragma unroll
    for (int j = 0; j < 6; ++j){
      long oi = pix*CC + tx + 16*j;
      float v = b2f(xmid[oi]) + acc[i][j];
      if (f) ((float*)outv)[oi] = v;
      else   ((bf16*)outv)[oi] = f2b(v);
    }
  }
}

extern "C" void kernel_launch(void* const* d_in, const int* in_sizes, int n_in,
                              void* d_out, int out_size, void* d_ws, size_t ws_size,
                              hipStream_t stream)
{
  long cum[22], cumP[22]; cum[0] = 0; cumP[0] = 0;
  for (int i = 0; i < 21; ++i){
    cum[i+1]  = cum[i]  + in_sizes[i];
    cumP[i+1] = cumP[i] + (((long)in_sizes[i] + 7) & ~7L);
  }
  long totalP = cumP[21];

  CvtArgs a;
  for (int i = 0; i < 21; ++i) a.src[i] = d_in[i];
  for (int i = 0; i < 22; ++i){ a.cum[i] = cum[i]; a.cumP[i] = cumP[i]; }

  char* ws = (char*)d_ws;
  int*  flag   = (int*)ws;
  bf16* packed = (bf16*)(ws + 1048576);

  detect_kernel<<<1, 256, 0, stream>>>((const unsigned*)d_in[0], flag);
  cvt_kernel<<<(int)((totalP/8 + 255) / 256), 256, 0, stream>>>(a, flag, packed, totalP);

  #define PP(i) (packed + cumP[i])
  const bf16* xc    = PP(0);
  const bf16* rc    = PP(1);
  const bf16* n1g   = PP(2);
  const bf16* n1b   = PP(3);
  const bf16* qkv_w = PP(4);
  const bf16* qkv_b = PP(5);
  const bf16* lsc   = PP(6);
  const bf16* gat   = PP(7);
  const bf16* rpbt  = PP(8);
  const bf16* tw    = PP(9);
  const bf16* tb    = PP(10);
  const bf16* pw    = PP(11);
  const bf16* pb    = PP(12);
  const bf16* n2g   = PP(13);
  const bf16* n2b   = PP(14);
  const bf16* f1w   = PP(15);
  const bf16* f1b   = PP(16);
  const bf16* cmw   = PP(17);
  const bf16* cmb   = PP(18);
  const bf16* f2w   = PP(19);
  const bf16* f2bp  = PP(20);

  bf16* wtc  = (bf16*)(ws + 52860928);
  bf16* wtm  = (bf16*)(ws + 53598208);
  bf16* xn   = (bf16*)(ws + 54525952);
  bf16* rn   = (bf16*)(ws + 79691776);
  bf16* img  = (bf16*)(ws + 104857600);
  bf16* rtr  = xn;
  bf16* xmid = xn;
  bf16* ln2o = rn;
  bf16* h1   = (bf16*)(ws + 1048576);
  bf16* hc   = rn;

  wprep_kernel<<<1440, 256, 0, stream>>>(tw, wtc, 96, 96, 368640);
  wprep_kernel<<<1440, 256, 0, stream>>>(cmw, wtm, 192, 192, 368640);

  ln1_kernel<<<65536, 256, 0, stream>>>(xc, rc, n1g, n1b, xn, rn);
  attn_kernel<<<2048, 256, 0, stream>>>(xn, rn, qkv_w, qkv_b, lsc, gat, rpbt, img);

  convmfma_kernel<96,96,0><<<dim3(16,32,2), 256, 0, stream>>>(img, wtc + 0L*92160, tb + 0,   nullptr, rtr);
  convmfma_kernel<96,96,1><<<dim3(16,32,2), 256, 0, stream>>>(rtr, wtc + 1L*92160, tb + 96,  img,     img);
  convmfma_kernel<96,96,0><<<dim3(16,32,2), 256, 0, stream>>>(img, wtc + 2L*92160, tb + 192, nullptr, rtr);
  convmfma_kernel<96,96,1><<<dim3(16,32,2), 256, 0, stream>>>(rtr, wtc + 3L*92160, tb + 288, img,     img);

  proj_kernel<<<2048, 256, 0, stream>>>(img, pw, pb, xc, xmid);
  ln2_kernel<<<32768, 256, 0, stream>>>(xmid, n2g, n2b, ln2o);
  fc1_kernel<<<2048, 256, 0, stream>>>(ln2o, f1w, f1b, h1);
  convmfma_kernel<192,192,2><<<dim3(16,32,4), 256, 0, stream>>>(h1, wtm, cmb, nullptr, hc);
  fc2_kernel<<<2048, 256, 0, stream>>>(hc, f2w, f2bp, xmid, d_out, flag);
}

// Round 7
// 885.089 us; speedup vs baseline: 1.0585x; 1.0585x over previous
//
#include <hip/hip_runtime.h>
#include <hip/hip_bf16.h>

// Shapes (fixed by the reference)
#define BB 2
#define HH 256
#define WWID 256
#define CC 96
#define NHEADS 6
#define WSZ 8
#define SHIFTV 4
#define HDIM 16
#define NTOK 64
#define HID 192
#define LL 65536   // H*W

using bf16 = __hip_bfloat16;
typedef short short8v __attribute__((ext_vector_type(8)));
typedef float float4v __attribute__((ext_vector_type(4)));

__device__ __forceinline__ float b2f(bf16 v){ return __bfloat162float(v); }
__device__ __forceinline__ bf16  f2b(float f){ return __float2bfloat16(f); }
__device__ __forceinline__ float blo(unsigned u){ union {unsigned x; float f;} c; c.x = u << 16; return c.f; }
__device__ __forceinline__ float bhi(unsigned u){ union {unsigned x; float f;} c; c.x = u & 0xffff0000u; return c.f; }

__device__ __forceinline__ float dot8(uint4 a, uint4 b, float acc){
  acc += blo(a.x)*blo(b.x); acc += bhi(a.x)*bhi(b.x);
  acc += blo(a.y)*blo(b.y); acc += bhi(a.y)*bhi(b.y);
  acc += blo(a.z)*blo(b.z); acc += bhi(a.z)*bhi(b.z);
  acc += blo(a.w)*blo(b.w); acc += bhi(a.w)*bhi(b.w);
  return acc;
}

// async 16B global->LDS DMA (dest = wave-uniform base + lane*16)
__device__ __forceinline__ void gload16(const void* g, void* l){
  __builtin_amdgcn_global_load_lds(
      (const __attribute__((address_space(1))) unsigned int*)g,
      (__attribute__((address_space(3))) unsigned int*)l, 16, 0, 0);
}

// LDS granule swizzle (pitch 12 granules of 16B).
__device__ __forceinline__ int swz(int c8, int r){
  return (c8 < 8) ? (c8 ^ (r & 7)) : (8 + ((c8 & 3) ^ ((r >> 1) & 3)));
}

// ---------------- input dtype detection -------------------------------------
__global__ void detect_kernel(const unsigned* __restrict__ x, int* __restrict__ flag){
  __shared__ int s[256];
  int t = threadIdx.x;
  int cnt = 0;
  #pragma unroll
  for (int i = 0; i < 4; ++i){
    unsigned u = x[t*4 + i];
    unsigned e = (u >> 7) & 0xFFu;
    cnt += (e >= 118u && e <= 130u) ? 1 : 0;
  }
  s[t] = cnt; __syncthreads();
  for (int m = 128; m > 0; m >>= 1){ if (t < m) s[t] += s[t+m]; __syncthreads(); }
  if (t == 0) *flag = (s[0] < 512) ? 1 : 0;
}

// ---------------- convert all inputs into one packed bf16 block -------------
struct CvtArgs { const void* src[21]; long cum[22]; long cumP[22]; };

__global__ void cvt_kernel(CvtArgs a, const int* __restrict__ flag,
                           bf16* __restrict__ dst, long totalP){
  long k0 = ((long)blockIdx.x * 256 + threadIdx.x) * 8;
  if (k0 >= totalP) return;
  int lo = 0;
  #pragma unroll
  for (int i = 0; i < 21; ++i) if (k0 >= a.cumP[i+1]) lo = i+1;
  long e = k0 - a.cumP[lo];
  long n = a.cum[lo+1] - a.cum[lo];
  int f = *flag;
  __align__(16) bf16 ob[8];
  if (e + 8 <= n){
    if (f){
      const float* s = (const float*)a.src[lo] + e;
      float4 v0 = *(const float4*)s;
      float4 v1 = *(const float4*)(s + 4);
      ob[0]=f2b(v0.x); ob[1]=f2b(v0.y); ob[2]=f2b(v0.z); ob[3]=f2b(v0.w);
      ob[4]=f2b(v1.x); ob[5]=f2b(v1.y); ob[6]=f2b(v1.z); ob[7]=f2b(v1.w);
    } else {
      *(uint4*)ob = *(const uint4*)((const bf16*)a.src[lo] + e);
    }
  } else {
    #pragma unroll
    for (int j = 0; j < 8; ++j){
      long ee = e + j;
      ob[j] = (ee < n) ? (f ? f2b(((const float*)a.src[lo])[ee])
                            : ((const bf16*)a.src[lo])[ee])
                       : f2b(0.f);
    }
  }
  *(uint4*)&dst[k0] = *(uint4*)ob;
}

// ---------------- weight prepack: w[tap][cin][cout] -> swizzled LDS image ---
__global__ void wprep_kernel(const bf16* __restrict__ w, bf16* __restrict__ out,
                             int CINr, int COUTr, long total){
  long k = (long)blockIdx.x * 256 + threadIdx.x;
  if (k >= total) return;
  int NHr = COUTr / 96, CHr = CINr / 96;
  int region = (int)(k / 10240); int rem = (int)(k - (long)region*10240);
  int gg = rem >> 3, e = rem & 7;
  if (gg >= 1152){ out[k] = f2b(0.f); return; }
  int r = gg / 12, pos = gg - r*12;
  int ch = region % CHr; int t2 = region / CHr;
  int nhh = t2 % NHr; int tap = t2 / NHr;
  int c8 = (pos < 8) ? (pos ^ (r & 7)) : (8 + ((pos & 3) ^ ((r >> 1) & 3)));
  int cin = ch*96 + c8*8 + e;
  int cout = nhh*96 + r;
  out[k] = w[((long)tap*CINr + cin)*COUTr + cout];
}

// ---------------- LayerNorm1 on x and ref (bf16 in -> bf16 out) -------------
__global__ __launch_bounds__(256) void ln1_kernel(const bf16* __restrict__ x, const bf16* __restrict__ ref,
                                                  const bf16* __restrict__ g, const bf16* __restrict__ bt,
                                                  bf16* __restrict__ xn, bf16* __restrict__ rn)
{
  int wave = threadIdx.x >> 6, lane = threadIdx.x & 63;
  long row = (long)blockIdx.x * 4 + wave;         // 0 .. 2*BB*LL-1
  const bf16* src; bf16* dst; long r;
  if (row < (long)BB*LL){ src = x; dst = xn; r = row; }
  else                  { src = ref; dst = rn; r = row - (long)BB*LL; }
  const bf16* p = src + r*CC;
  float v0 = b2f(p[lane]);
  float v1 = (lane < 32) ? b2f(p[64+lane]) : 0.f;
  float s = v0 + v1;
  #pragma unroll
  for (int m = 32; m >= 1; m >>= 1) s += __shfl_xor(s, m, 64);
  float mu = s * (1.f/CC);
  float d0 = v0 - mu, d1 = v1 - mu;
  float ss = d0*d0 + ((lane < 32) ? d1*d1 : 0.f);
  #pragma unroll
  for (int m = 32; m >= 1; m >>= 1) ss += __shfl_xor(ss, m, 64);
  float rstd = rsqrtf(ss * (1.f/CC) + 1e-5f);
  bf16* q = dst + r*CC;
  q[lane] = f2b(d0 * rstd * b2f(g[lane]) + b2f(bt[lane]));
  if (lane < 32) q[64+lane] = f2b(d1 * rstd * b2f(g[64+lane]) + b2f(bt[64+lane]));
}

// ---------------- LayerNorm2 (bf16 in -> bf16 out) --------------------------
__global__ __launch_bounds__(256) void ln2_kernel(const bf16* __restrict__ xin,
                                                  const bf16* __restrict__ g, const bf16* __restrict__ bt,
                                                  bf16* __restrict__ out)
{
  int wave = threadIdx.x >> 6, lane = threadIdx.x & 63;
  long r = (long)blockIdx.x * 4 + wave;           // 0 .. BB*LL-1
  const bf16* p = xin + r*CC;
  float v0 = b2f(p[lane]);
  float v1 = (lane < 32) ? b2f(p[64+lane]) : 0.f;
  float s = v0 + v1;
  #pragma unroll
  for (int m = 32; m >= 1; m >>= 1) s += __shfl_xor(s, m, 64);
  float mu = s * (1.f/CC);
  float d0 = v0 - mu, d1 = v1 - mu;
  float ss = d0*d0 + ((lane < 32) ? d1*d1 : 0.f);
  #pragma unroll
  for (int m = 32; m >= 1; m >>= 1) ss += __shfl_xor(ss, m, 64);
  float rstd = rsqrtf(ss * (1.f/CC) + 1e-5f);
  bf16* q = out + r*CC;
  q[lane] = f2b(d0 * rstd * b2f(g[lane]) + b2f(bt[lane]));
  if (lane < 32) q[64+lane] = f2b(d1 * rstd * b2f(g[64+lane]) + b2f(bt[64+lane]));
}

// ---------------- Fused window attention, MFMA everywhere -------------------
// v3: exp2-domain softmax (v_exp_f32), rpb-index/mask hoisted out of the head
//     loop, qs/ks/krs pitch 20 (2-way stores, K-pad via cndmask not LDS).
//     LDS 49,544 B -> 3 blocks/CU.
__global__ __launch_bounds__(256, 3) void attn_kernel(const bf16* __restrict__ xn, const bf16* __restrict__ rn,
                                                      const bf16* __restrict__ qkv_w, const bf16* __restrict__ qkv_b,
                                                      const bf16* __restrict__ lsc, const bf16* __restrict__ gat,
                                                      const bf16* __restrict__ rpbt, bf16* __restrict__ img)
{
  __shared__ __align__(16) bf16 sx[NTOK][104];    // 13312 B
  __shared__ __align__(16) bf16 sr[NTOK][104];    // 13312 B
  __shared__ __align__(16) bf16 wps[48*104];      //  9984 B  union: wb[48][104] / ps[64][76]
  __shared__ float sbias[48];                     //   192 B
  __shared__ __align__(16) bf16 qs[NTOK][20];     //  2560 B  qn (pitch 20: 2-way stores)
  __shared__ __align__(16) bf16 ks[NTOK][20];     //  2560 B  kn
  __shared__ __align__(16) bf16 krs[NTOK][20];    //  2560 B  kn_ref
  __shared__ __align__(16) bf16 vt[16][72];       //  2304 B  V^T [d][tok]
  __shared__ __align__(16) bf16 vrt[16][72];      //  2304 B  Vr^T
  __shared__ __align__(16) bf16 rpbs[228];        //   456 B  rpb head slice (bf16)
  // total 49,544 B -> 3 blocks/CU

  bf16 (*wb)[104] = (bf16(*)[104])&wps[0];
  bf16 (*ps)[76]  = (bf16(*)[76])&wps[0];

  const float L2E = 1.4426950408889634f;

  int widx = blockIdx.x;
  int b = widx >> 10, wib = widx & 1023;
  int wh = wib >> 5, ww = wib & 31;
  int tid = threadIdx.x;
  int wv = tid >> 6, lane = tid & 63;
  int ml = lane & 15, quad = lane >> 4;

  for (int idx = tid; idx < NTOK*12; idx += 256){
    int n = idx / 12, c8 = idx - n*12;
    int i = n >> 3, j = n & 7;
    int h0 = (wh*8 + i + SHIFTV) & 255;
    int w0 = (ww*8 + j + SHIFTV) & 255;
    long base = (((long)b*HH + h0)*WWID + w0)*CC + c8*8;
    *(uint4*)&sx[n][c8*8] = *(const uint4*)&xn[base];
    *(uint4*)&sr[n][c8*8] = *(const uint4*)&rn[base];
  }

  // hoist rpb index + mask (head-independent): lane holds q-row ti = wv*16+ml,
  // columns tj = nt*16 + quad*4 + r
  int ti = wv*16 + ml;
  int iy = ti >> 3, ix = ti & 7;
  int regi = ((wh < 31) ? 0 : (iy < 4 ? 1 : 2))*3 + ((ww < 31) ? 0 : (ix < 4 ? 1 : 2));
  int idxm[16];
  #pragma unroll
  for (int nt = 0; nt < 4; ++nt){
    #pragma unroll
    for (int r = 0; r < 4; ++r){
      int tj = nt*16 + quad*4 + r;
      int jy = tj >> 3, jx = tj & 7;
      int regj = ((wh < 31) ? 0 : (jy < 4 ? 1 : 2))*3 + ((ww < 31) ? 0 : (jx < 4 ? 1 : 2));
      int idx = (iy - jy + 7)*15 + (ix - jx + 7);
      idxm[nt*4 + r] = idx | ((regi != regj) ? 0x8000 : 0);
    }
  }

  for (int h = 0; h < NHEADS; ++h){
    __syncthreads();  // prev head's ps/qs/vt reads done before restage
    for (int idx = tid; idx < 48*12; idx += 256){
      int rr = idx / 12, c8 = idx - rr*12;
      int o = (rr >> 4)*CC + h*HDIM + (rr & 15);
      *(uint4*)&wb[rr][c8*8] = *(const uint4*)&qkv_w[(long)o*CC + c8*8];
    }
    if (tid < 48){
      int o = (tid >> 4)*CC + h*HDIM + (tid & 15);
      sbias[tid] = b2f(qkv_b[o]);
    }
    if (tid < 225) rpbs[tid] = rpbt[tid*NHEADS + h];
    __syncthreads();

    // ---- QKV via MFMA: wave wv owns token rows wv*16..+15 ----
    float4v aq0 = {0,0,0,0}, aq1 = {0,0,0,0}, aq2 = {0,0,0,0};
    float4v ar0 = {0,0,0,0}, ar1 = {0,0,0,0};
    {
      int arow = wv*16 + ml;
      #pragma unroll
      for (int kt = 0; kt < 3; ++kt){
        int ko = kt*32 + quad*8;
        short8v ax = *(const short8v*)&sx[arow][ko];
        short8v av = *(const short8v*)&sr[arow][ko];
        short8v b0 = *(const short8v*)&wb[ml][ko];
        short8v b1 = *(const short8v*)&wb[16+ml][ko];
        short8v b2 = *(const short8v*)&wb[32+ml][ko];
        aq0 = __builtin_amdgcn_mfma_f32_16x16x32_bf16(ax, b0, aq0, 0,0,0);
        aq1 = __builtin_amdgcn_mfma_f32_16x16x32_bf16(ax, b1, aq1, 0,0,0);
        aq2 = __builtin_amdgcn_mfma_f32_16x16x32_bf16(ax, b2, aq2, 0,0,0);
        ar0 = __builtin_amdgcn_mfma_f32_16x16x32_bf16(av, b1, ar0, 0,0,0);
        ar1 = __builtin_amdgcn_mfma_f32_16x16x32_bf16(av, b2, ar1, 0,0,0);
      }
    }
    // ---- epilogue: bias + in-register l2 norm (reduce over ml lanes) ----
    {
      float bq = sbias[ml], bk = sbias[16+ml], bv = sbias[32+ml];
      #pragma unroll
      for (int r = 0; r < 4; ++r){
        float qv  = aq0[r] + bq;
        float kv  = aq1[r] + bk;
        float krv = ar0[r] + bk;
        float sq = qv*qv, sk = kv*kv, skr = krv*krv;
        #pragma unroll
        for (int m = 1; m < 16; m <<= 1){
          sq  += __shfl_xor(sq,  m, 64);
          sk  += __shfl_xor(sk,  m, 64);
          skr += __shfl_xor(skr, m, 64);
        }
        float iq  = 1.f / fmaxf(sqrtf(sq),  1e-12f);
        float ik  = 1.f / fmaxf(sqrtf(sk),  1e-12f);
        float ikr = 1.f / fmaxf(sqrtf(skr), 1e-12f);
        int tok = wv*16 + quad*4 + r;
        qs[tok][ml]  = f2b(qv*iq);
        ks[tok][ml]  = f2b(kv*ik);
        krs[tok][ml] = f2b(krv*ikr);
        vt[ml][tok]  = f2b(aq2[r] + bv);
        vrt[ml][tok] = f2b(ar1[r] + bv);
      }
    }
    __syncthreads();

    float ls2 = expf(fminf(b2f(lsc[h]), 4.605170185988091f)) * L2E;
    float gv = b2f(gat[h]);
    float g = 1.f / (1.f + expf(-gv));

    // ---- S^T via swapped MFMA (K-pad via cndmask: d16..31 zero) ----
    float4v s1[4], s2[4];
    {
      int qoff = (quad & 1) * 8;             // valid read for all quads
      short8v z8 = {0,0,0,0,0,0,0,0};
      short8v qf = *(const short8v*)&qs[wv*16 + ml][qoff];
      qf = (quad < 2) ? qf : z8;
      #pragma unroll
      for (int nt = 0; nt < 4; ++nt){
        short8v kf  = *(const short8v*)&ks[nt*16 + ml][qoff];
        short8v krf = *(const short8v*)&krs[nt*16 + ml][qoff];
        kf  = (quad < 2) ? kf  : z8;
        krf = (quad < 2) ? krf : z8;
        float4v zz = {0,0,0,0};
        s1[nt] = __builtin_amdgcn_mfma_f32_16x16x32_bf16(kf,  qf, zz, 0,0,0);
        s2[nt] = __builtin_amdgcn_mfma_f32_16x16x32_bf16(krf, qf, zz, 0,0,0);
      }
    }
    // ---- scale + bias in log2 domain ----
    float sv1[4][4], sv2[4][4];
    #pragma unroll
    for (int nt = 0; nt < 4; ++nt){
      #pragma unroll
      for (int r = 0; r < 4; ++r){
        int u = idxm[nt*4 + r];
        float rp = b2f(rpbs[u & 0x1FF]);
        float base = rp*L2E + ((u & 0x8000) ? -144.2695040889f : 0.f);
        sv1[nt][r] = fmaf(s1[nt][r], ls2, base);
        sv2[nt][r] = fmaf(s2[nt][r], ls2, base);
      }
    }
    // ---- softmax (base 2): local 16-max + 2 cross-quad shuffles ----
    float mx1 = -1e30f, mx2 = -1e30f;
    #pragma unroll
    for (int nt = 0; nt < 4; ++nt)
      #pragma unroll
      for (int r = 0; r < 4; ++r){ mx1 = fmaxf(mx1, sv1[nt][r]); mx2 = fmaxf(mx2, sv2[nt][r]); }
    mx1 = fmaxf(mx1, __shfl_xor(mx1, 16, 64)); mx1 = fmaxf(mx1, __shfl_xor(mx1, 32, 64));
    mx2 = fmaxf(mx2, __shfl_xor(mx2, 16, 64)); mx2 = fmaxf(mx2, __shfl_xor(mx2, 32, 64));
    float sm1 = 0.f, sm2 = 0.f;
    #pragma unroll
    for (int nt = 0; nt < 4; ++nt)
      #pragma unroll
      for (int r = 0; r < 4; ++r){
        sv1[nt][r] = exp2f(sv1[nt][r] - mx1); sm1 += sv1[nt][r];
        sv2[nt][r] = exp2f(sv2[nt][r] - mx2); sm2 += sv2[nt][r];
      }
    sm1 += __shfl_xor(sm1, 16, 64); sm1 += __shfl_xor(sm1, 32, 64);
    sm2 += __shfl_xor(sm2, 16, 64); sm2 += __shfl_xor(sm2, 32, 64);
    float f1 = (1.f - g) / sm1;
    float f2 = g / sm2;

    // ---- PV path 1: packed b64 P writes (wave-private rows) ----
    #pragma unroll
    for (int nt = 0; nt < 4; ++nt){
      __align__(8) bf16 pk[4];
      #pragma unroll
      for (int r = 0; r < 4; ++r) pk[r] = f2b(sv1[nt][r] * f1);
      *(short4*)&ps[ti][nt*16 + quad*4] = *(short4*)pk;
    }
    float4v po = {0,0,0,0};
    #pragma unroll
    for (int kt = 0; kt < 2; ++kt){
      short8v pa = *(const short8v*)&ps[wv*16 + ml][kt*32 + quad*8];
      short8v vb = *(const short8v*)&vt[ml][kt*32 + quad*8];
      po = __builtin_amdgcn_mfma_f32_16x16x32_bf16(pa, vb, po, 0,0,0);
    }
    // ---- PV path 2 (reuse ps) ----
    #pragma unroll
    for (int nt = 0; nt < 4; ++nt){
      __align__(8) bf16 pk[4];
      #pragma unroll
      for (int r = 0; r < 4; ++r) pk[r] = f2b(sv2[nt][r] * f2);
      *(short4*)&ps[ti][nt*16 + quad*4] = *(short4*)pk;
    }
    #pragma unroll
    for (int kt = 0; kt < 2; ++kt){
      short8v pa = *(const short8v*)&ps[wv*16 + ml][kt*32 + quad*8];
      short8v vb = *(const short8v*)&vrt[ml][kt*32 + quad*8];
      po = __builtin_amdgcn_mfma_f32_16x16x32_bf16(pa, vb, po, 0,0,0);
    }
    // ---- write out (shifted coords); po[r] = O[wv*16+quad*4+r][ml] ----
    #pragma unroll
    for (int r = 0; r < 4; ++r){
      int tok = wv*16 + quad*4 + r;
      int hs = wh*8 + (tok >> 3), wsp = ww*8 + (tok & 7);
      img[(((long)b*HH + hs)*WWID + wsp)*CC + h*HDIM + ml] = f2b(po[r]);
    }
  }
}

// ---------------- MFMA implicit-GEMM 3x3 conv (NHWC, pad 1) -----------------
template<int CIN, int COUT, int MODE>
__global__ __launch_bounds__(256) void convmfma_kernel(const bf16* __restrict__ src,
                                                       const bf16* __restrict__ wtp,
                                                       const bf16* __restrict__ bias,
                                                       const bf16* __restrict__ base,
                                                       bf16* __restrict__ dst)
{
  constexpr int CH = CIN / 96;
  constexpr int NH = COUT / 96;
  constexpr int NS = CH * 9;
  __shared__ __align__(16) bf16 act[180*12*8];   // 34,560 B
  __shared__ __align__(16) bf16 wl[2][1280*8];   // 2 x 20,480 B

  int tid = threadIdx.x;
  int z = blockIdx.z;
  int bb = z / NH;
  int nh = z % NH;
  int tx0 = blockIdx.x * 16, ty0 = blockIdx.y * 8;
  int wv = tid >> 6, lane = tid & 63;

  auto stage_act = [&](int h){
    for (int idx = tid; idx < 180*12; idx += 256){
      int pp = idx / 12, c8 = idx - pp*12;
      int iy = pp / 18, ix = pp - iy*18;
      int gy = ty0 + iy - 1, gx = tx0 + ix - 1;
      uint4 v = make_uint4(0,0,0,0);
      if ((unsigned)gy < (unsigned)HH && (unsigned)gx < (unsigned)WWID)
        v = *(const uint4*)&src[(((long)bb*HH + gy)*WWID + gx)*CIN + h*96 + c8*8];
      *(uint4*)&act[(pp*12 + swz(c8, pp))*8] = v;
    }
  };
  auto gloadW = [&](int s, int buf){
    int hh = s / 9, tap = s - hh*9;
    int region = (tap*NH + nh)*CH + hh;
    const bf16* g = wtp + (long)region*10240 + (wv*320 + lane)*8;
    bf16* l = &wl[buf][(wv*320)*8];
    #pragma unroll
    for (int i = 0; i < 5; ++i)
      gload16(g + i*512, l + i*512);
  };

  int wm = wv >> 1, wn = wv & 1;
  int ml = lane & 15, quad = lane >> 4;

  float4v acc[4][3];
  #pragma unroll
  for (int nt = 0; nt < 3; ++nt){
    float bv = b2f(bias[nh*96 + wn*48 + nt*16 + ml]);
    #pragma unroll
    for (int mt = 0; mt < 4; ++mt)
      acc[mt][nt] = (float4v){bv, bv, bv, bv};
  }

  int apy = ml >> 3, apx = wm*8 + (ml & 7);

  stage_act(0);
  gloadW(0, 0);
  if (NS > 1) gloadW(1, 1);
  __syncthreads();

  for (int s = 0; s < NS; ++s){
    int h = s / 9, tap = s - h*9;
    int cur = s & 1;
    int dy = tap / 3, dx = tap - dy*3;
    #pragma unroll
    for (int kc = 0; kc < 3; ++kc){
      int posB = (kc < 2) ? ((kc*4 + quad) ^ (ml & 7)) : (8 + (quad ^ ((ml >> 1) & 3)));
      int brow = wn*48 + ml;
      short8v b0 = *(const short8v*)&wl[cur][((brow     )*12 + posB)*8];
      short8v b1 = *(const short8v*)&wl[cur][((brow + 16)*12 + posB)*8];
      short8v b2 = *(const short8v*)&wl[cur][((brow + 32)*12 + posB)*8];
      #pragma unroll
      for (int mt = 0; mt < 4; ++mt){
        int pp = (mt*2 + apy + dy)*18 + apx + dx;
        int posA = (kc < 2) ? ((kc*4 + quad) ^ (pp & 7)) : (8 + (quad ^ ((pp >> 1) & 3)));
        short8v a = *(const short8v*)&act[(pp*12 + posA)*8];
        acc[mt][0] = __builtin_amdgcn_mfma_f32_16x16x32_bf16(a, b0, acc[mt][0], 0, 0, 0);
        acc[mt][1] = __builtin_amdgcn_mfma_f32_16x16x32_bf16(a, b1, acc[mt][1], 0, 0, 0);
        acc[mt][2] = __builtin_amdgcn_mfma_f32_16x16x32_bf16(a, b2, acc[mt][2], 0, 0, 0);
      }
    }
    if (s + 1 == NS) break;
    __syncthreads();
    if (s + 2 < NS) gloadW(s + 2, cur);
    if (tap == 8){
      stage_act(h + 1);
      __syncthreads();
    }
  }

  #pragma unroll
  for (int mt = 0; mt < 4; ++mt){
    #pragma unroll
    for (int r = 0; r < 4; ++r){
      int mrow = quad*4 + r;
      int py = mt*2 + (mrow >> 3), px = wm*8 + (mrow & 7);
      long ob = (((long)bb*HH + ty0+py)*WWID + tx0+px)*COUT + nh*96 + wn*48 + ml;
      #pragma unroll
      for (int nt = 0; nt < 3; ++nt){
        float v = acc[mt][nt][r];
        long o = ob + nt*16;
        if (MODE == 0)      dst[o] = f2b(fmaxf(v, 0.f));
        else if (MODE == 1) dst[o] = f2b(b2f(base[o]) + v);
        else                dst[o] = f2b(0.5f * v * (1.f + erff(v * 0.7071067811865476f)));
      }
    }
  }
}

// ---------------- proj (96x96) + roll-back(+4,+4) + shortcut -> bf16 xmid ---
#define PPITCH (CC+8)
__global__ __launch_bounds__(256) void proj_kernel(const bf16* __restrict__ img, const bf16* __restrict__ pw,
                                                   const bf16* __restrict__ pb, const bf16* __restrict__ xorig,
                                                   bf16* __restrict__ xmid)
{
  __shared__ __align__(16) bf16 rows[64][PPITCH];
  __shared__ __align__(16) bf16 wsm[CC][PPITCH];
  long pix0 = (long)blockIdx.x * 64;
  int tid = threadIdx.x;
  for (int idx = tid; idx < 64*CC; idx += 256){
    int pp = idx / CC, c = idx - pp*CC;
    long pix = pix0 + pp;
    int b = (int)(pix >> 16); int hw = (int)(pix & 65535);
    int h = hw >> 8, wc = hw & 255;
    int sh = (h - SHIFTV) & 255, sw = (wc - SHIFTV) & 255;
    rows[pp][c] = img[(((long)b*HH + sh)*WWID + sw)*CC + c];
  }
  for (int idx = tid; idx < CC*CC; idx += 256){
    int rr = idx / CC, c = idx - rr*CC;
    wsm[rr][c] = pw[idx];
  }
  __syncthreads();
  int ty = tid >> 4, tx = tid & 15;
  int r0 = ty*4;
  float acc[4][6];
  #pragma unroll
  for (int j = 0; j < 6; ++j){
    float bv = b2f(pb[tx + 16*j]);
    #pragma unroll
    for (int i = 0; i < 4; ++i) acc[i][j] = bv;
  }
  for (int kk = 0; kk < 12; ++kk){
    uint4 a0 = ((const uint4*)rows[r0+0])[kk];
    uint4 a1 = ((const uint4*)rows[r0+1])[kk];
    uint4 a2 = ((const uint4*)rows[r0+2])[kk];
    uint4 a3 = ((const uint4*)rows[r0+3])[kk];
    #pragma unroll
    for (int j = 0; j < 6; ++j){
      uint4 wv = ((const uint4*)wsm[tx + 16*j])[kk];
      acc[0][j] = dot8(a0, wv, acc[0][j]);
      acc[1][j] = dot8(a1, wv, acc[1][j]);
      acc[2][j] = dot8(a2, wv, acc[2][j]);
      acc[3][j] = dot8(a3, wv, acc[3][j]);
    }
  }
  #pragma unroll
  for (int i = 0; i < 4; ++i){
    long pix = pix0 + r0 + i;
    #pragma unroll
    for (int j = 0; j < 6; ++j){
      long oi = pix*CC + tx + 16*j;
      xmid[oi] = f2b(b2f(xorig[oi]) + acc[i][j]);
    }
  }
}

// ---------------- fc1: 96->192 + exact GELU ---------------------------------
__global__ __launch_bounds__(256) void fc1_kernel(const bf16* __restrict__ src, const bf16* __restrict__ w,
                                                  const bf16* __restrict__ bias, bf16* __restrict__ dst)
{
  __shared__ __align__(16) bf16 rows[64][PPITCH];
  __shared__ __align__(16) bf16 wsm[HID][PPITCH];
  long pix0 = (long)blockIdx.x * 64;
  int tid = threadIdx.x;
  for (int idx = tid; idx < 64*CC; idx += 256){
    int pp = idx / CC, c = idx - pp*CC;
    rows[pp][c] = src[(pix0 + pp)*CC + c];
  }
  for (int idx = tid; idx < HID*CC; idx += 256){
    int rr = idx / CC, c = idx - rr*CC;
    wsm[rr][c] = w[idx];
  }
  __syncthreads();
  int ty = tid >> 4, tx = tid & 15;
  int r0 = ty*4;
  float acc[4][12];
  #pragma unroll
  for (int j = 0; j < 12; ++j){
    float bv = b2f(bias[tx + 16*j]);
    #pragma unroll
    for (int i = 0; i < 4; ++i) acc[i][j] = bv;
  }
  for (int kk = 0; kk < 12; ++kk){
    uint4 a0 = ((const uint4*)rows[r0+0])[kk];
    uint4 a1 = ((const uint4*)rows[r0+1])[kk];
    uint4 a2 = ((const uint4*)rows[r0+2])[kk];
    uint4 a3 = ((const uint4*)rows[r0+3])[kk];
    #pragma unroll
    for (int j = 0; j < 12; ++j){
      uint4 wv = ((const uint4*)wsm[tx + 16*j])[kk];
      acc[0][j] = dot8(a0, wv, acc[0][j]);
      acc[1][j] = dot8(a1, wv, acc[1][j]);
      acc[2][j] = dot8(a2, wv, acc[2][j]);
      acc[3][j] = dot8(a3, wv, acc[3][j]);
    }
  }
  #pragma unroll
  for (int i = 0; i < 4; ++i){
    long pix = pix0 + r0 + i;
    #pragma unroll
    for (int j = 0; j < 12; ++j){
      float v = acc[i][j];
      dst[pix*HID + tx + 16*j] = f2b(0.5f * v * (1.f + erff(v * 0.7071067811865476f)));
    }
  }
}

// ---------------- fc2: 192->96 + bf16 xmid residual -> out (flag dtype) -----
#define FPITCH (HID+8)
__global__ __launch_bounds__(256) void fc2_kernel(const bf16* __restrict__ src, const bf16* __restrict__ w,
                                                  const bf16* __restrict__ bias, const bf16* __restrict__ xmid,
                                                  void* __restrict__ outv, const int* __restrict__ flag)
{
  __shared__ __align__(16) bf16 rows[64][FPITCH];
  __shared__ __align__(16) bf16 wsm[CC][FPITCH];
  long pix0 = (long)blockIdx.x * 64;
  int tid = threadIdx.x;
  for (int idx = tid; idx < 64*HID; idx += 256){
    int pp = idx / HID, c = idx - pp*HID;
    rows[pp][c] = src[(pix0 + pp)*HID + c];
  }
  for (int idx = tid; idx < CC*HID; idx += 256){
    int rr = idx / HID, c = idx - rr*HID;
    wsm[rr][c] = w[idx];
  }
  __syncthreads();
  int ty = tid >> 4, tx = tid & 15;
  int r0 = ty*4;
  float acc[4][6];
  #pragma unroll
  for (int j = 0; j < 6; ++j){
    float bv = b2f(bias[tx + 16*j]);
    #pragma unroll
    for (int i = 0; i < 4; ++i) acc[i][j] = bv;
  }
  for (int kk = 0; kk < 24; ++kk){
    uint4 a0 = ((const uint4*)rows[r0+0])[kk];
    uint4 a1 = ((const uint4*)rows[r0+1])[kk];
    uint4 a2 = ((const uint4*)rows[r0+2])[kk];
    uint4 a3 = ((const uint4*)rows[r0+3])[kk];
    #pragma unroll
    for (int j = 0; j < 6; ++j){
      uint4 wv = ((const uint4*)wsm[tx + 16*j])[kk];
      acc[0][j] = dot8(a0, wv, acc[0][j]);
      acc[1][j] = dot8(a1, wv, acc[1][j]);
      acc[2][j] = dot8(a2, wv, acc[2][j]);
      acc[3][j] = dot8(a3, wv, acc[3][j]);
    }
  }
  int f = *flag;
  #pragma unroll
  for (int i = 0; i < 4; ++i){
    long pix = pix0 + r0 + i;
    #pragma unroll
    for (int j = 0; j < 6; ++j){
      long oi = pix*CC + tx + 16*j;
      float v = b2f(xmid[oi]) + acc[i][j];
      if (f) ((float*)outv)[oi] = v;
      else   ((bf16*)outv)[oi] = f2b(v);
    }
  }
}

extern "C" void kernel_launch(void* const* d_in, const int* in_sizes, int n_in,
                              void* d_out, int out_size, void* d_ws, size_t ws_size,
                              hipStream_t stream)
{
  long cum[22], cumP[22]; cum[0] = 0; cumP[0] = 0;
  for (int i = 0; i < 21; ++i){
    cum[i+1]  = cum[i]  + in_sizes[i];
    cumP[i+1] = cumP[i] + (((long)in_sizes[i] + 7) & ~7L);
  }
  long totalP = cumP[21];

  CvtArgs a;
  for (int i = 0; i < 21; ++i) a.src[i] = d_in[i];
  for (int i = 0; i < 22; ++i){ a.cum[i] = cum[i]; a.cumP[i] = cumP[i]; }

  char* ws = (char*)d_ws;
  int*  flag   = (int*)ws;
  bf16* packed = (bf16*)(ws + 1048576);

  detect_kernel<<<1, 256, 0, stream>>>((const unsigned*)d_in[0], flag);
  cvt_kernel<<<(int)((totalP/8 + 255) / 256), 256, 0, stream>>>(a, flag, packed, totalP);

  #define PP(i) (packed + cumP[i])
  const bf16* xc    = PP(0);
  const bf16* rc    = PP(1);
  const bf16* n1g   = PP(2);
  const bf16* n1b   = PP(3);
  const bf16* qkv_w = PP(4);
  const bf16* qkv_b = PP(5);
  const bf16* lsc   = PP(6);
  const bf16* gat   = PP(7);
  const bf16* rpbt  = PP(8);
  const bf16* tw    = PP(9);
  const bf16* tb    = PP(10);
  const bf16* pw    = PP(11);
  const bf16* pb    = PP(12);
  const bf16* n2g   = PP(13);
  const bf16* n2b   = PP(14);
  const bf16* f1w   = PP(15);
  const bf16* f1b   = PP(16);
  const bf16* cmw   = PP(17);
  const bf16* cmb   = PP(18);
  const bf16* f2w   = PP(19);
  const bf16* f2bp  = PP(20);

  bf16* wtc  = (bf16*)(ws + 52860928);
  bf16* wtm  = (bf16*)(ws + 53598208);
  bf16* xn   = (bf16*)(ws + 54525952);
  bf16* rn   = (bf16*)(ws + 79691776);
  bf16* img  = (bf16*)(ws + 104857600);
  bf16* rtr  = xn;
  bf16* xmid = xn;
  bf16* ln2o = rn;
  bf16* h1   = (bf16*)(ws + 1048576);
  bf16* hc   = rn;

  wprep_kernel<<<1440, 256, 0, stream>>>(tw, wtc, 96, 96, 368640);
  wprep_kernel<<<1440, 256, 0, stream>>>(cmw, wtm, 192, 192, 368640);

  ln1_kernel<<<65536, 256, 0, stream>>>(xc, rc, n1g, n1b, xn, rn);
  attn_kernel<<<2048, 256, 0, stream>>>(xn, rn, qkv_w, qkv_b, lsc, gat, rpbt, img);

  convmfma_kernel<96,96,0><<<dim3(16,32,2), 256, 0, stream>>>(img, wtc + 0L*92160, tb + 0,   nullptr, rtr);
  convmfma_kernel<96,96,1><<<dim3(16,32,2), 256, 0, stream>>>(rtr, wtc + 1L*92160, tb + 96,  img,     img);
  convmfma_kernel<96,96,0><<<dim3(16,32,2), 256, 0, stream>>>(img, wtc + 2L*92160, tb + 192, nullptr, rtr);
  convmfma_kernel<96,96,1><<<dim3(16,32,2), 256, 0, stream>>>(rtr, wtc + 3L*92160, tb + 288, img,     img);

  proj_kernel<<<2048, 256, 0, stream>>>(img, pw, pb, xc, xmid);
  ln2_kernel<<<32768, 256, 0, stream>>>(xmid, n2g, n2b, ln2o);
  fc1_kernel<<<2048, 256, 0, stream>>>(ln2o, f1w, f1b, h1);
  convmfma_kernel<192,192,2><<<dim3(16,32,4), 256, 0, stream>>>(h1, wtm, cmb, nullptr, hc);
  fc2_kernel<<<2048, 256, 0, stream>>>(hc, f2w, f2bp, xmid, d_out, flag);
}